// Round 1
// baseline (293.958 us; speedup 1.0000x reference)
//
#include <hip/hip_runtime.h>
#include <stdint.h>

// Top-K (K=64) per row of [4096, 32768] f32, relu'd, scattered into zeros.
//
// Strategy: one 1024-thread block per row.
//  Phase 0 (streaming, HBM-bound): read row as float4, convert to
//    order-preserving uint32, stage in LDS, write zeros to the output row,
//    build a 2048-bucket LDS histogram of the top 11 bits.
//  Radix select: find the bucket containing the 64th-largest; refine with
//    two more 11/10-bit levels over the LDS copy until either the cumulative
//    count hits exactly 64 at a bucket edge (simple threshold) or we have the
//    exact 32-bit boundary value T with ties (then pick lowest-index equals
//    via a block-ordered prefix scan — matches jax.lax.top_k tie-break).
//  Scatter: scan LDS copy, write relu(value) for the <=64 selected positions.

#define LROW     32768
#define NTHREADS 1024
#define KSEL     64u

// float bits -> order-preserving uint (bigger uint == bigger float)
__device__ __forceinline__ uint32_t f2o(uint32_t b) {
    return b ^ (uint32_t)(((int32_t)b >> 31) | 0x80000000u);
}
// inverse transform
__device__ __forceinline__ float o2f(uint32_t u) {
    uint32_t b = (u & 0x80000000u) ? (u ^ 0x80000000u) : ~u;
    return __uint_as_float(b);
}

// Wave 0 scans hist[nb-1 .. 0] from the top, finds bucket b* such that
// cum_before < need <= cum_before + hist[b*]; writes {b*, cum_before, hist[b*]}
// to ctrl[0..2]. Caller must __syncthreads() after.
__device__ __forceinline__ void wave0_select(uint32_t* ctrl, const uint32_t* hist,
                                             int nb, uint32_t need,
                                             int tid, int lane)
{
    if (tid < 64) {
        uint32_t cum = 0;
        int done = 0;
        for (int base = nb; base > 0 && !done; base -= 64) {
            uint32_t c = hist[base - 1 - lane];   // lane 0 = highest bucket
            uint32_t inc = c;
            #pragma unroll
            for (int off = 1; off < 64; off <<= 1) {
                uint32_t t = __shfl_up(inc, off);
                if (lane >= off) inc += t;
            }
            uint32_t tot = __shfl(inc, 63);
            uint32_t pre = inc - c;               // exclusive prefix (buckets above me this chunk)
            bool hit = (cum + pre < need) && (cum + pre + c >= need);
            if (hit) {                            // at most one lane can hit
                ctrl[0] = (uint32_t)(base - 1 - lane);
                ctrl[1] = cum + pre;
                ctrl[2] = c;
            }
            done = (__ballot(hit) != 0ull);
            cum += tot;
        }
    }
}

__global__ __launch_bounds__(NTHREADS, 1) void topk_scatter_kernel(
    const float* __restrict__ x, float* __restrict__ out)
{
    extern __shared__ uint32_t sm[];
    uint32_t* rowu = sm;               // LROW entries: staged ordered-uint row
    uint32_t* hist = sm + LROW;        // 2048 buckets
    uint32_t* ctrl = hist + 2048;      // 64: [0..2] select result, [16..31] wave sums

    const int tid  = threadIdx.x;
    const int lane = tid & 63;
    const int wid  = tid >> 6;
    const size_t rowoff = (size_t)blockIdx.x * LROW;
    const float4* __restrict__ xin  = (const float4*)(x + rowoff);
    float4*       __restrict__ xout = (float4*)(out + rowoff);

    hist[tid] = 0u;
    hist[tid + 1024] = 0u;
    __syncthreads();

    // ---- Phase 0: stream in + zero out + level-0 histogram ----
    #pragma unroll
    for (int j = 0; j < LROW / (NTHREADS * 4); ++j) {
        int p = j * NTHREADS + tid;            // float4 index
        float4 v = xin[p];
        uint32_t u0 = f2o(__float_as_uint(v.x));
        uint32_t u1 = f2o(__float_as_uint(v.y));
        uint32_t u2 = f2o(__float_as_uint(v.z));
        uint32_t u3 = f2o(__float_as_uint(v.w));
        uint4 uu; uu.x = u0; uu.y = u1; uu.z = u2; uu.w = u3;
        ((uint4*)rowu)[p] = uu;
        float4 z; z.x = 0.f; z.y = 0.f; z.z = 0.f; z.w = 0.f;
        xout[p] = z;
        atomicAdd(&hist[u0 >> 21], 1u);
        atomicAdd(&hist[u1 >> 21], 1u);
        atomicAdd(&hist[u2 >> 21], 1u);
        atomicAdd(&hist[u3 >> 21], 1u);
    }
    __syncthreads();

    // ---- Level 0 select (top 11 bits) ----
    wave0_select(ctrl, hist, 2048, KSEL, tid, lane);
    __syncthreads();
    uint32_t b0 = ctrl[0], cum0 = ctrl[1], bc0 = ctrl[2];

    uint32_t Tcut = 0;
    bool     incEq = false;
    bool     tie = false;
    uint32_t tieR = 0;
    bool     resolved = false;

    if (cum0 + bc0 == KSEL) {        // whole bucket included exactly
        Tcut = b0 << 21; incEq = true; resolved = true;
    }

    if (!resolved) {
        uint32_t need1 = KSEL - cum0;
        __syncthreads();
        hist[tid] = 0u; hist[tid + 1024] = 0u;
        __syncthreads();
        // ---- Level 1 histogram (bits 20..10) over elements in bucket b0 ----
        #pragma unroll
        for (int j = 0; j < LROW / (NTHREADS * 4); ++j) {
            uint4 uu = ((uint4*)rowu)[j * NTHREADS + tid];
            if ((uu.x >> 21) == b0) atomicAdd(&hist[(uu.x >> 10) & 0x7FFu], 1u);
            if ((uu.y >> 21) == b0) atomicAdd(&hist[(uu.y >> 10) & 0x7FFu], 1u);
            if ((uu.z >> 21) == b0) atomicAdd(&hist[(uu.z >> 10) & 0x7FFu], 1u);
            if ((uu.w >> 21) == b0) atomicAdd(&hist[(uu.w >> 10) & 0x7FFu], 1u);
        }
        __syncthreads();
        wave0_select(ctrl, hist, 2048, need1, tid, lane);
        __syncthreads();
        uint32_t b1 = ctrl[0], cum1 = ctrl[1], bc1 = ctrl[2];
        uint32_t P20 = (b0 << 11) | b1;        // top 22 bits of threshold

        if (cum1 + bc1 == need1) {
            Tcut = P20 << 10; incEq = true; resolved = true;
        }

        if (!resolved) {
            uint32_t need2 = need1 - cum1;
            __syncthreads();
            hist[tid] = 0u;                    // only 1024 buckets this level
            __syncthreads();
            // ---- Level 2 histogram (bits 9..0) over elements matching P20 ----
            #pragma unroll
            for (int j = 0; j < LROW / (NTHREADS * 4); ++j) {
                uint4 uu = ((uint4*)rowu)[j * NTHREADS + tid];
                if ((uu.x >> 10) == P20) atomicAdd(&hist[uu.x & 0x3FFu], 1u);
                if ((uu.y >> 10) == P20) atomicAdd(&hist[uu.y & 0x3FFu], 1u);
                if ((uu.z >> 10) == P20) atomicAdd(&hist[uu.z & 0x3FFu], 1u);
                if ((uu.w >> 10) == P20) atomicAdd(&hist[uu.w & 0x3FFu], 1u);
            }
            __syncthreads();
            wave0_select(ctrl, hist, 1024, need2, tid, lane);
            __syncthreads();
            uint32_t b2 = ctrl[0], cum2 = ctrl[1], ceq = ctrl[2];
            uint32_t T = (P20 << 10) | b2;     // exact 32-bit boundary value
            uint32_t r = need2 - cum2;         // how many equal-to-T to include
            Tcut = T;
            if (r == ceq) { incEq = true; }
            else          { incEq = false; tie = true; tieR = r; }
        }
    }

    // ---- Tie path: include the tieR lowest-index elements equal to Tcut ----
    if (tie) {
        int base = tid * (LROW / NTHREADS);    // contiguous chunk, index order
        uint32_t c = 0;
        #pragma unroll 4
        for (int j = 0; j < LROW / NTHREADS; ++j) c += (rowu[base + j] == Tcut);
        uint32_t inc = c;
        #pragma unroll
        for (int off = 1; off < 64; off <<= 1) {
            uint32_t t = __shfl_up(inc, off);
            if (lane >= off) inc += t;
        }
        if (lane == 63) ctrl[16 + wid] = inc;  // wave totals
        __syncthreads();
        if (tid < 16) {
            uint32_t v = ctrl[16 + tid];
            uint32_t inc2 = v;
            #pragma unroll
            for (int off = 1; off < 16; off <<= 1) {
                uint32_t t = __shfl_up(inc2, off);
                if (lane >= off) inc2 += t;
            }
            ctrl[16 + tid] = inc2 - v;         // exclusive wave base
        }
        __syncthreads();
        uint32_t rank = ctrl[16 + wid] + (inc - c);
        float tv = fmaxf(o2f(Tcut), 0.0f);
        for (int j = 0; j < LROW / NTHREADS; ++j) {
            if (rowu[base + j] == Tcut) {
                if (rank < tieR) out[rowoff + base + j] = tv;
                rank++;
            }
        }
    }

    // ---- Scatter: write relu(value) for selected elements ----
    #pragma unroll
    for (int j = 0; j < LROW / (NTHREADS * 4); ++j) {
        int p = j * NTHREADS + tid;
        uint4 uu = ((uint4*)rowu)[p];
        int col = p * 4;
        if ((uu.x > Tcut) || (incEq && uu.x == Tcut))
            out[rowoff + col + 0] = fmaxf(o2f(uu.x), 0.0f);
        if ((uu.y > Tcut) || (incEq && uu.y == Tcut))
            out[rowoff + col + 1] = fmaxf(o2f(uu.y), 0.0f);
        if ((uu.z > Tcut) || (incEq && uu.z == Tcut))
            out[rowoff + col + 2] = fmaxf(o2f(uu.z), 0.0f);
        if ((uu.w > Tcut) || (incEq && uu.w == Tcut))
            out[rowoff + col + 3] = fmaxf(o2f(uu.w), 0.0f);
    }
}

extern "C" void kernel_launch(void* const* d_in, const int* in_sizes, int n_in,
                              void* d_out, int out_size, void* d_ws, size_t ws_size,
                              hipStream_t stream)
{
    const float* x = (const float*)d_in[0];
    float* out = (float*)d_out;
    int rows = in_sizes[0] / LROW;   // 4096

    size_t smem = (size_t)(LROW + 2048 + 64) * sizeof(uint32_t);  // ~136.3 KiB
    topk_scatter_kernel<<<rows, NTHREADS, smem, stream>>>(x, out);
}

// Round 3
// 259.041 us; speedup vs baseline: 1.1348x; 1.1348x over previous
//
#include <hip/hip_runtime.h>
#include <stdint.h>

// Top-K (K=64) per row of [4096, 32768] f32, relu'd, scattered into zeros.
//
// Round-3 = round-2 design with a compile fix (nontemporal store needs a
// native vector type, not HIP's float4 class).
//
//  - One 1024-thread block per row, TWO blocks per CU (73.3 KiB LDS).
//  - LDS stages only 16-bit keys (top 16 bits of order-preserving uint32).
//  - Phase 0 streams: read float4, write zero (non-temporal), pack 4 keys
//    to LDS (8B), histogram top-8 key bits (256 buckets, LDS atomics).
//  - Select: two 8-bit radix levels -> exact 16-bit threshold T16 with
//    either clean cut (incEq) or a tie at T16.
//  - Tie at T16: gather positions of ==T16 elements (expected ~4), re-read
//    full f32 values, exact rank by (value desc, index asc) — matches
//    jax.lax.top_k. Cold fallback (multiplicity > 1024) refines to the
//    exact 32-bit threshold with global re-reads.
//  - Scatter: scan LDS keys; winners re-read value from global, write relu.

#define LROW     32768
#define NT       1024
#define KSEL     64u
#define LISTCAP  1024

typedef float vf4 __attribute__((ext_vector_type(4)));

// float bits -> order-preserving uint (bigger uint == bigger float)
__device__ __forceinline__ uint32_t f2o(uint32_t b) {
    return b ^ (uint32_t)(((int32_t)b >> 31) | 0x80000000u);
}
__device__ __forceinline__ float o2f(uint32_t u) {
    uint32_t b = (u & 0x80000000u) ? (u ^ 0x80000000u) : ~u;
    return __uint_as_float(b);
}

// Wave 0 scans hist[nb-1..0] from the top; finds bucket b* with
// cum_before < need <= cum_before + hist[b*]; writes {b*, cum_before, hist[b*]}
// to ctrl[0..2]. Caller syncs before (hist ready) and after (result visible).
__device__ __forceinline__ void wave0_select(uint32_t* ctrl, const uint32_t* hist,
                                             int nb, uint32_t need,
                                             int tid, int lane)
{
    if (tid < 64) {
        uint32_t cum = 0;
        int done = 0;
        for (int base = nb; base > 0 && !done; base -= 64) {
            uint32_t c = hist[base - 1 - lane];   // lane 0 = highest bucket
            uint32_t inc = c;
            #pragma unroll
            for (int off = 1; off < 64; off <<= 1) {
                uint32_t t = __shfl_up(inc, off);
                if (lane >= off) inc += t;
            }
            uint32_t tot = __shfl(inc, 63);
            uint32_t pre = inc - c;
            bool hit = (cum + pre < need) && (cum + pre + c >= need);
            if (hit) {
                ctrl[0] = (uint32_t)(base - 1 - lane);
                ctrl[1] = cum + pre;
                ctrl[2] = c;
            }
            done = (__ballot(hit) != 0ull);
            cum += tot;
        }
    }
}

__global__ __launch_bounds__(NT, 8) void topk_kernel(
    const float* __restrict__ x, float* __restrict__ out)
{
    extern __shared__ uint32_t sm[];
    // layout (u32 words): keys 16384 | hist 256 | plist 1024 | ulist 1024 | ctrl 64
    uint32_t* keysw = sm;                    // 32768 x u16 packed
    uint32_t* hist  = sm + 16384;
    uint32_t* plist = hist + 256;
    uint32_t* ulist = plist + 1024;
    uint32_t* ctrl  = ulist + 1024;

    const int tid  = threadIdx.x;
    const int lane = tid & 63;
    const int wid  = tid >> 6;
    const size_t rowoff = (size_t)blockIdx.x * LROW;
    const float4* __restrict__ xin  = (const float4*)(x + rowoff);
    vf4*          __restrict__ xout = (vf4*)(out + rowoff);

    if (tid < 256) hist[tid] = 0u;
    if (tid == 0)  ctrl[3] = 0u;             // tie-list counter
    __syncthreads();

    // ---- Phase 0: stream in + zero out + top-8-bit histogram + key staging ----
    #pragma unroll
    for (int j = 0; j < LROW / (NT * 4); ++j) {
        int p = j * NT + tid;                // float4 index
        float4 v = xin[p];
        uint32_t k0 = f2o(__float_as_uint(v.x)) >> 16;
        uint32_t k1 = f2o(__float_as_uint(v.y)) >> 16;
        uint32_t k2 = f2o(__float_as_uint(v.z)) >> 16;
        uint32_t k3 = f2o(__float_as_uint(v.w)) >> 16;
        uint2 pk; pk.x = k0 | (k1 << 16); pk.y = k2 | (k3 << 16);
        ((uint2*)keysw)[p] = pk;
        vf4 z = (vf4)(0.0f);
        __builtin_nontemporal_store(z, &xout[p]);
        atomicAdd(&hist[k0 >> 8], 1u);
        atomicAdd(&hist[k1 >> 8], 1u);
        atomicAdd(&hist[k2 >> 8], 1u);
        atomicAdd(&hist[k3 >> 8], 1u);
    }
    __syncthreads();

    // ---- Level 0 select (top 8 of 16 key bits) ----
    wave0_select(ctrl, hist, 256, KSEL, tid, lane);
    __syncthreads();
    uint32_t b0 = ctrl[0], cum0 = ctrl[1], bc0 = ctrl[2];

    uint32_t T16;
    bool incEq;
    bool tie = false;
    uint32_t tieR = 0, tieM = 0;

    if (cum0 + bc0 == KSEL) {
        T16 = b0 << 8; incEq = true;         // whole bucket in, exact 64
    } else {
        uint32_t need1 = KSEL - cum0;
        __syncthreads();
        if (tid < 256) hist[tid] = 0u;
        __syncthreads();
        // ---- Level 1 histogram (low 8 key bits) for keys in bucket b0 ----
        #pragma unroll
        for (int j = 0; j < LROW / (NT * 4); ++j) {
            uint2 pk = ((const uint2*)keysw)[j * NT + tid];
            uint32_t k0 = pk.x & 0xFFFFu, k1 = pk.x >> 16;
            uint32_t k2 = pk.y & 0xFFFFu, k3 = pk.y >> 16;
            if ((k0 >> 8) == b0) atomicAdd(&hist[k0 & 0xFFu], 1u);
            if ((k1 >> 8) == b0) atomicAdd(&hist[k1 & 0xFFu], 1u);
            if ((k2 >> 8) == b0) atomicAdd(&hist[k2 & 0xFFu], 1u);
            if ((k3 >> 8) == b0) atomicAdd(&hist[k3 & 0xFFu], 1u);
        }
        __syncthreads();
        wave0_select(ctrl, hist, 256, need1, tid, lane);
        __syncthreads();
        uint32_t b1 = ctrl[0], cum1 = ctrl[1], bc1 = ctrl[2];
        T16 = (b0 << 8) | b1;
        uint32_t needEq = need1 - cum1;      // 1..bc1
        if (needEq == bc1) { incEq = true; }
        else { incEq = false; tie = true; tieR = needEq; tieM = bc1; }
    }

    // ---- Tie at 16-bit threshold: exact resolve with full values ----
    if (tie) {
        if (tieM <= LISTCAP) {
            // gather (pos, full ordered value) of all ==T16 elements
            #pragma unroll
            for (int j = 0; j < LROW / (NT * 4); ++j) {
                int p = j * NT + tid;
                uint2 pk = ((const uint2*)keysw)[p];
                uint32_t kk0 = pk.x & 0xFFFFu, kk1 = pk.x >> 16;
                uint32_t kk2 = pk.y & 0xFFFFu, kk3 = pk.y >> 16;
                uint32_t km[4] = {kk0, kk1, kk2, kk3};
                #pragma unroll
                for (int q = 0; q < 4; ++q) {
                    if (km[q] == T16) {
                        uint32_t idx = atomicAdd(&ctrl[3], 1u);
                        uint32_t pos = (uint32_t)(p * 4 + q);
                        plist[idx] = pos;
                        ulist[idx] = f2o(__float_as_uint(x[rowoff + pos]));
                    }
                }
            }
            __syncthreads();
            uint32_t m = tieM;
            if ((uint32_t)tid < m) {
                uint32_t myu = ulist[tid], myp = plist[tid];
                uint32_t rank = 0;
                for (uint32_t j2 = 0; j2 < m; ++j2) {
                    uint32_t uj = ulist[j2], pj = plist[j2];
                    rank += (uj > myu) || (uj == myu && pj < myp);
                }
                if (rank < tieR) {
                    float v = o2f(myu);
                    if (v > 0.f) out[rowoff + myp] = v;   // relu; 0 == background
                }
            }
        } else {
            // ---- Cold fallback: refine to exact 32-bit threshold (global re-reads) ----
            __syncthreads();
            if (tid < 256) hist[tid] = 0u;
            __syncthreads();
            #pragma unroll
            for (int j = 0; j < LROW / (NT * 4); ++j) {
                float4 v = xin[j * NT + tid];
                uint32_t u[4] = { f2o(__float_as_uint(v.x)), f2o(__float_as_uint(v.y)),
                                  f2o(__float_as_uint(v.z)), f2o(__float_as_uint(v.w)) };
                #pragma unroll
                for (int q = 0; q < 4; ++q)
                    if ((u[q] >> 16) == T16) atomicAdd(&hist[(u[q] >> 8) & 0xFFu], 1u);
            }
            __syncthreads();
            wave0_select(ctrl, hist, 256, tieR, tid, lane);
            __syncthreads();
            uint32_t b2 = ctrl[0], cum2 = ctrl[1];
            uint32_t P24 = (T16 << 8) | b2;
            uint32_t need3 = tieR - cum2;
            __syncthreads();
            if (tid < 256) hist[tid] = 0u;
            __syncthreads();
            #pragma unroll
            for (int j = 0; j < LROW / (NT * 4); ++j) {
                float4 v = xin[j * NT + tid];
                uint32_t u[4] = { f2o(__float_as_uint(v.x)), f2o(__float_as_uint(v.y)),
                                  f2o(__float_as_uint(v.z)), f2o(__float_as_uint(v.w)) };
                #pragma unroll
                for (int q = 0; q < 4; ++q)
                    if ((u[q] >> 8) == P24) atomicAdd(&hist[u[q] & 0xFFu], 1u);
            }
            __syncthreads();
            wave0_select(ctrl, hist, 256, need3, tid, lane);
            __syncthreads();
            uint32_t b3 = ctrl[0], cum3 = ctrl[1];
            uint32_t T32 = (P24 << 8) | b3;
            uint32_t r4 = need3 - cum3;      // #(==T32) to include, lowest index first
            // ordered prefix over contiguous chunks for index tie-break
            int cbase = tid * (LROW / NT);
            uint32_t c = 0;
            for (int j = 0; j < LROW / NT; ++j)
                c += (f2o(__float_as_uint(x[rowoff + cbase + j])) == T32);
            uint32_t inc = c;
            #pragma unroll
            for (int off = 1; off < 64; off <<= 1) {
                uint32_t t = __shfl_up(inc, off);
                if (lane >= off) inc += t;
            }
            if (lane == 63) ctrl[16 + wid] = inc;
            __syncthreads();
            if (tid < 16) {
                uint32_t v = ctrl[16 + tid];
                uint32_t inc2 = v;
                #pragma unroll
                for (int off = 1; off < 16; off <<= 1) {
                    uint32_t t = __shfl_up(inc2, off);
                    if (lane >= off) inc2 += t;
                }
                ctrl[16 + tid] = inc2 - v;   // exclusive wave base
            }
            __syncthreads();
            uint32_t rank = ctrl[16 + wid] + (inc - c);
            for (int j = 0; j < LROW / NT; ++j) {
                uint32_t u = f2o(__float_as_uint(x[rowoff + cbase + j]));
                if ((u >> 16) == T16 && u > T32) {
                    float v = o2f(u);
                    if (v > 0.f) out[rowoff + cbase + j] = v;
                }
                if (u == T32) {
                    if (rank < r4) {
                        float v = o2f(u);
                        if (v > 0.f) out[rowoff + cbase + j] = v;
                    }
                    rank++;
                }
            }
        }
    }

    // ---- Scatter: winners strictly above T16 (plus ==T16 when incEq) ----
    #pragma unroll
    for (int j = 0; j < LROW / (NT * 4); ++j) {
        int p = j * NT + tid;
        uint2 pk = ((const uint2*)keysw)[p];
        uint32_t kk0 = pk.x & 0xFFFFu, kk1 = pk.x >> 16;
        uint32_t kk2 = pk.y & 0xFFFFu, kk3 = pk.y >> 16;
        uint32_t km[4] = {kk0, kk1, kk2, kk3};
        #pragma unroll
        for (int q = 0; q < 4; ++q) {
            bool win = (km[q] > T16) || (incEq && km[q] == T16);
            if (win) {
                float v = x[rowoff + p * 4 + q];
                if (v > 0.f) out[rowoff + p * 4 + q] = v;
            }
        }
    }
}

extern "C" void kernel_launch(void* const* d_in, const int* in_sizes, int n_in,
                              void* d_out, int out_size, void* d_ws, size_t ws_size,
                              hipStream_t stream)
{
    const float* x = (const float*)d_in[0];
    float* out = (float*)d_out;
    int rows = in_sizes[0] / LROW;   // 4096

    // u32 words: 16384 keys + 256 hist + 1024 plist + 1024 ulist + 64 ctrl
    size_t smem = (size_t)(16384 + 256 + 1024 + 1024 + 64) * sizeof(uint32_t); // 73.25 KiB
    topk_kernel<<<rows, NT, smem, stream>>>(x, out);
}

// Round 4
// 248.507 us; speedup vs baseline: 1.1829x; 1.0424x over previous
//
#include <hip/hip_runtime.h>
#include <stdint.h>

// Top-K (K=64) per row of [4096, 32768] f32, relu'd, scattered into zeros.
//
// Round-4 design: candidate compaction instead of full-row histogramming.
//  - One 512-thread block per row, FOUR blocks per CU (33.3 KiB LDS, 32 waves).
//  - Phase 0 streams: read float4, zero the output row (non-temporal), and
//    append elements with ordered-key >= UCUT (= +2.0f) to an LDS candidate
//    list (ballot-compacted append; expected ~745 candidates for N(0,1)).
//    NO per-element histogram, NO 64KB key staging -> the LDS-atomic
//    serialization that dominated rounds 1-3 is gone.
//  - Exact select over the M candidates: 4 radix levels of 8 bits on the full
//    32-bit ordered key (256-bucket LDS histogram, trivial at M~745), giving
//    the exact 64th-largest key T32 and r = #(==T32) to include. Equal keys
//    are included lowest-index-first (matches jax.lax.top_k).
//  - Scatter: winners written straight from the candidate list (key -> float);
//    all candidates are >= 2.0 so relu is a no-op on this path.
//  - Fallback (M < 64 or M > CAP, never taken for this input, exactness
//    insurance): full 32-bit radix select with global re-reads (11/11/10 bit
//    levels), ordered tie-break, relu applied explicitly.

#define LROW   32768
#define NT     512
#define NWAVE  (NT / 64)
#define ITERS  (LROW / (NT * 4))   // 16
#define KSEL   64u
#define CAP    4096u
#define UCUT   0xC0000000u         // f2o(+2.0f)

typedef float vf4 __attribute__((ext_vector_type(4)));

// float bits -> order-preserving uint (bigger uint == bigger float)
__device__ __forceinline__ uint32_t f2o(uint32_t b) {
    return b ^ (uint32_t)(((int32_t)b >> 31) | 0x80000000u);
}
__device__ __forceinline__ float o2f(uint32_t u) {
    uint32_t b = (u & 0x80000000u) ? (u ^ 0x80000000u) : ~u;
    return __uint_as_float(b);
}

// Wave 0 scans hist[nb-1..0] from the top; finds bucket b* with
// cum_before < need <= cum_before + hist[b*]; writes {b*, cum_before, hist[b*]}
// to ctrl[0..2]. Caller syncs before (hist ready) and after (result visible).
__device__ __forceinline__ void wave0_select(uint32_t* ctrl, const uint32_t* hist,
                                             int nb, uint32_t need,
                                             int tid, int lane)
{
    if (tid < 64) {
        uint32_t cum = 0;
        int done = 0;
        for (int base = nb; base > 0 && !done; base -= 64) {
            uint32_t c = hist[base - 1 - lane];   // lane 0 = highest bucket
            uint32_t inc = c;
            #pragma unroll
            for (int off = 1; off < 64; off <<= 1) {
                uint32_t t = __shfl_up(inc, off);
                if (lane >= off) inc += t;
            }
            uint32_t tot = __shfl(inc, 63);
            uint32_t pre = inc - c;
            bool hit = (cum + pre < need) && (cum + pre + c >= need);
            if (hit) {
                ctrl[0] = (uint32_t)(base - 1 - lane);
                ctrl[1] = cum + pre;
                ctrl[2] = c;
            }
            done = (__ballot(hit) != 0ull);
            cum += tot;
        }
    }
}

__global__ __launch_bounds__(NT, 8) void topk_kernel(
    const float* __restrict__ x, float* __restrict__ out)
{
    __shared__ uint32_t cu[CAP];     // candidate ordered keys (fallback: big hist)
    __shared__ uint32_t cp[CAP];     // candidate positions
    __shared__ uint32_t hist[256];
    __shared__ uint32_t ctrl[64];

    const int tid  = threadIdx.x;
    const int lane = tid & 63;
    const int wid  = tid >> 6;
    const size_t rowoff = (size_t)blockIdx.x * LROW;
    const float4* __restrict__ xin  = (const float4*)(x + rowoff);
    vf4*          __restrict__ xout = (vf4*)(out + rowoff);

    if (tid == 0) ctrl[3] = 0u;      // candidate-append counter
    __syncthreads();

    // ---- Phase 0: stream (read + zero-store) + compact candidates ----
    #pragma unroll
    for (int j = 0; j < ITERS; ++j) {
        int p = j * NT + tid;        // float4 index
        float4 v = xin[p];
        uint32_t u0 = f2o(__float_as_uint(v.x));
        uint32_t u1 = f2o(__float_as_uint(v.y));
        uint32_t u2 = f2o(__float_as_uint(v.z));
        uint32_t u3 = f2o(__float_as_uint(v.w));
        vf4 z = (vf4)(0.0f);
        __builtin_nontemporal_store(z, &xout[p]);
        uint32_t uu[4] = {u0, u1, u2, u3};
        #pragma unroll
        for (int q = 0; q < 4; ++q) {
            bool isc = (uu[q] >= UCUT);
            unsigned long long mk = __ballot(isc);
            if (isc) {
                int lpre = __popcll(mk & ((1ull << lane) - 1ull));
                uint32_t base = 0;
                int lead = (int)(__ffsll((long long)mk) - 1);
                if (lane == lead)
                    base = atomicAdd(&ctrl[3], (uint32_t)__popcll(mk));
                base = __shfl(base, lead);
                uint32_t idx = base + (uint32_t)lpre;
                if (idx < CAP) {
                    cu[idx] = uu[q];
                    cp[idx] = (uint32_t)(p * 4 + q);
                }
            }
        }
    }
    __syncthreads();
    uint32_t M = ctrl[3];

    if (M >= KSEL && M <= CAP) {
        // ---- Main path: exact 4x8-bit radix select over M candidates ----
        uint32_t need = KSEL;
        uint32_t pref = 0;
        uint32_t cnt  = 0;
        #pragma unroll
        for (int L = 3; L >= 0; --L) {
            __syncthreads();
            if (tid < 256) hist[tid] = 0u;
            __syncthreads();
            for (uint32_t i = tid; i < M; i += NT) {
                uint32_t u = cu[i];
                bool inb = (L == 3) || ((u >> ((L + 1) * 8)) == pref);
                if (inb) atomicAdd(&hist[(u >> (L * 8)) & 0xFFu], 1u);
            }
            __syncthreads();
            wave0_select(ctrl, hist, 256, need, tid, lane);
            __syncthreads();
            uint32_t d = ctrl[0], cum = ctrl[1];
            cnt = ctrl[2];
            pref = (pref << 8) | d;
            need = need - cum;        // 1..cnt
        }
        uint32_t T32 = pref;
        uint32_t r   = need;          // #(==T32) to include, lowest index first

        // ---- Scatter winners from the candidate list ----
        for (uint32_t i = tid; i < M; i += NT) {
            uint32_t u = cu[i];
            if (u > T32) {
                out[rowoff + cp[i]] = o2f(u);     // u >= UCUT -> value >= 2 > 0
            } else if (u == T32) {
                bool take = (r == cnt);
                if (!take) {
                    uint32_t myp = cp[i], rank = 0;
                    for (uint32_t j2 = 0; j2 < M; ++j2)
                        rank += (cu[j2] == T32 && cp[j2] < myp);
                    take = (rank < r);
                }
                if (take) out[rowoff + cp[i]] = o2f(u);
            }
        }
        return;
    }

    // ---- Fallback: exact 32-bit radix over global re-reads (correctness
    //      insurance; statistically never taken for N(0,1) rows) ----
    uint32_t* hist2 = cu;            // 2048-entry histogram in candidate space

    // Level A: bits 31:21
    for (int i = tid; i < 2048; i += NT) hist2[i] = 0u;
    __syncthreads();
    for (int j = 0; j < ITERS; ++j) {
        float4 v = xin[j * NT + tid];
        uint32_t u[4] = { f2o(__float_as_uint(v.x)), f2o(__float_as_uint(v.y)),
                          f2o(__float_as_uint(v.z)), f2o(__float_as_uint(v.w)) };
        #pragma unroll
        for (int q = 0; q < 4; ++q) atomicAdd(&hist2[u[q] >> 21], 1u);
    }
    __syncthreads();
    wave0_select(ctrl, hist2, 2048, KSEL, tid, lane);
    __syncthreads();
    uint32_t bA = ctrl[0], cumA = ctrl[1];
    uint32_t needB = KSEL - cumA;

    // Level B: bits 20:10 within bucket bA
    __syncthreads();
    for (int i = tid; i < 2048; i += NT) hist2[i] = 0u;
    __syncthreads();
    for (int j = 0; j < ITERS; ++j) {
        float4 v = xin[j * NT + tid];
        uint32_t u[4] = { f2o(__float_as_uint(v.x)), f2o(__float_as_uint(v.y)),
                          f2o(__float_as_uint(v.z)), f2o(__float_as_uint(v.w)) };
        #pragma unroll
        for (int q = 0; q < 4; ++q)
            if ((u[q] >> 21) == bA) atomicAdd(&hist2[(u[q] >> 10) & 0x7FFu], 1u);
    }
    __syncthreads();
    wave0_select(ctrl, hist2, 2048, needB, tid, lane);
    __syncthreads();
    uint32_t bB = ctrl[0], cumB = ctrl[1];
    uint32_t P22 = (bA << 11) | bB;
    uint32_t needC = needB - cumB;

    // Level C: bits 9:0 within prefix P22
    __syncthreads();
    for (int i = tid; i < 2048; i += NT) hist2[i] = 0u;
    __syncthreads();
    for (int j = 0; j < ITERS; ++j) {
        float4 v = xin[j * NT + tid];
        uint32_t u[4] = { f2o(__float_as_uint(v.x)), f2o(__float_as_uint(v.y)),
                          f2o(__float_as_uint(v.z)), f2o(__float_as_uint(v.w)) };
        #pragma unroll
        for (int q = 0; q < 4; ++q)
            if ((u[q] >> 10) == P22) atomicAdd(&hist2[u[q] & 0x3FFu], 1u);
    }
    __syncthreads();
    wave0_select(ctrl, hist2, 1024, needC, tid, lane);
    __syncthreads();
    uint32_t bC = ctrl[0], cumC = ctrl[1];
    uint32_t T32 = (P22 << 10) | bC;
    uint32_t r   = needC - cumC;     // #(==T32) to include, lowest index first

    // Ordered rank of ==T32 over contiguous chunks (index order), then scatter.
    const int cbase = tid * (LROW / NT);
    uint32_t c = 0;
    for (int j = 0; j < LROW / NT; ++j)
        c += (f2o(__float_as_uint(x[rowoff + cbase + j])) == T32);
    uint32_t inc = c;
    #pragma unroll
    for (int off = 1; off < 64; off <<= 1) {
        uint32_t t = __shfl_up(inc, off);
        if (lane >= off) inc += t;
    }
    if (lane == 63) ctrl[16 + wid] = inc;
    __syncthreads();
    if (tid < NWAVE) {
        uint32_t v = ctrl[16 + tid];
        uint32_t inc2 = v;
        #pragma unroll
        for (int off = 1; off < NWAVE; off <<= 1) {
            uint32_t t = __shfl_up(inc2, off);
            if (lane >= off) inc2 += t;
        }
        ctrl[16 + tid] = inc2 - v;   // exclusive wave base
    }
    __syncthreads();
    uint32_t rank = ctrl[16 + wid] + (inc - c);
    for (int j = 0; j < LROW / NT; ++j) {
        uint32_t u = f2o(__float_as_uint(x[rowoff + cbase + j]));
        bool take = false;
        if (u > T32) take = true;
        else if (u == T32) { take = (rank < r); rank++; }
        if (take) {
            float v = o2f(u);
            if (v > 0.f) out[rowoff + cbase + j] = v;   // relu; 0 == background
        }
    }
}

extern "C" void kernel_launch(void* const* d_in, const int* in_sizes, int n_in,
                              void* d_out, int out_size, void* d_ws, size_t ws_size,
                              hipStream_t stream)
{
    const float* x = (const float*)d_in[0];
    float* out = (float*)d_out;
    int rows = in_sizes[0] / LROW;   // 4096

    topk_kernel<<<rows, NT, 0, stream>>>(x, out);
}